// Round 14
// baseline (617.703 us; speedup 1.0000x reference)
//
#include <hip/hip_runtime.h>

// Problem constants (MeshConv: B=8, M=40000, FIN=64, K=6, FOUT=64, NNZ=320000)
#define Mn    40000
#define Bn    8
#define FINn  64
#define Kn    6
#define FOUTn 64
#define NNZn  320000
#define Cn    512   // FIN*B values per level row; c = b*64 + f
#define NB    ((Mn + 255) / 256)     // scan blocks = 157 (fallback path)
#define MT    (Mn / 64)              // 625 m-tiles for the GEMM
#define HGRID ((NNZn + 255) / 256)   // hist blocks = 1250 (fallback)
#define SCGRID ((NNZn + 255) / 256)  // scatter blocks = 1250
#define WFGRID 96                    // wfrag blocks
#define TGRID  (Mn / 4)              // transpose blocks = 10000
#define PADW  32                     // padded-CSR slots/row (R13-verified: max deg <= 32)

// Level layout (fp16): xh[lev][m][c] -- one row = 1KB contiguous.
// SpMM gathers one full 1KB row per edge (64 lanes x 16B, fully coalesced).

typedef _Float16 half8 __attribute__((ext_vector_type(8)));  // MFMA A/B frag
typedef __attribute__((ext_vector_type(4))) float floatx4;   // MFMA accumulator

__device__ __forceinline__ ushort f2h(float f) {
    _Float16 h = (_Float16)f;
    return *(ushort*)&h;
}

// async global->LDS, 16B per lane; dst must be wave-uniform base (HW adds lane*16)
__device__ __forceinline__ void gl_lds16(const ushort* g, ushort* l) {
    __builtin_amdgcn_global_load_lds(
        (const __attribute__((address_space(1))) unsigned int*)g,
        (__attribute__((address_space(3))) unsigned int*)l, 16, 0, 0);
}

// ---------------- shared device bodies ----------------

__device__ __forceinline__ void fmah8(float* a, uint4 g, float w) {
    union { uint4 u; _Float16 h[8]; } c; c.u = g;
#pragma unroll
    for (int i = 0; i < 8; ++i) a[i] += w * (float)c.h[i];
}

// R8-proven SpMM row body (fallback packed-CSR path).
__device__ __forceinline__ void spmm_row(const ushort* __restrict__ xc,
                                         const ushort* __restrict__ xp,
                                         ushort* __restrict__ xn,
                                         const int2* __restrict__ ce, int deg,
                                         int m, int lane, int first) {
    const uint4* xc4 = (const uint4*)xc;      // row = 64 uint4 (512 halves)
    uint4 v = xc4[(size_t)m * 64 + lane];
    uint4 p;
    if (!first) p = ((const uint4*)xp)[(size_t)m * 64 + lane];   // early issue
    float a[8];
    { union { uint4 u; _Float16 h[8]; } c; c.u = v;
#pragma unroll
      for (int i = 0; i < 8; ++i) a[i] = -(float)c.h[i]; }

    int i = 0;
    for (; i + 8 <= deg; i += 8) {
        int2 cv[8];
#pragma unroll
        for (int k = 0; k < 8; ++k) cv[k] = ce[i + k];
        uint4 g[8];
#pragma unroll
        for (int k = 0; k < 8; ++k) g[k] = xc4[(size_t)cv[k].x * 64 + lane];
#pragma unroll
        for (int k = 0; k < 8; ++k) fmah8(a, g[k], __int_as_float(cv[k].y));
    }
    for (; i + 4 <= deg; i += 4) {
        int2 cv0 = ce[i],     cv1 = ce[i + 1];
        int2 cv2 = ce[i + 2], cv3 = ce[i + 3];
        uint4 g0 = xc4[(size_t)cv0.x * 64 + lane];
        uint4 g1 = xc4[(size_t)cv1.x * 64 + lane];
        uint4 g2 = xc4[(size_t)cv2.x * 64 + lane];
        uint4 g3 = xc4[(size_t)cv3.x * 64 + lane];
        fmah8(a, g0, __int_as_float(cv0.y));
        fmah8(a, g1, __int_as_float(cv1.y));
        fmah8(a, g2, __int_as_float(cv2.y));
        fmah8(a, g3, __int_as_float(cv3.y));
    }
    for (; i < deg; ++i) {
        int2 cv = ce[i];
        uint4 g = xc4[(size_t)cv.x * 64 + lane];
        fmah8(a, g, __int_as_float(cv.y));
    }

    if (!first) {
        union { uint4 u; _Float16 h[8]; } c; c.u = p;
#pragma unroll
        for (int i2 = 0; i2 < 8; ++i2) a[i2] = 2.f * a[i2] - (float)c.h[i2];
    }
    union { uint4 u; _Float16 h[8]; } s;
#pragma unroll
    for (int i2 = 0; i2 < 8; ++i2) s.h[i2] = (_Float16)a[i2];
    ((uint4*)xn)[(size_t)m * 64 + lane] = s.u;
}

__device__ __forceinline__ void transpose_block(const float* __restrict__ x,
                                                ushort* __restrict__ x0h, int m0, int t) {
#pragma unroll
    for (int k = 0; k < 2; ++k) {
        int i   = t + k * 256;       // 0..511
        int ml  = i >> 7;            // 0..3
        int rem = i & 127;
        int b   = rem >> 4;
        int fq  = (rem & 15) * 4;
        float4 a = *(const float4*)(x + ((size_t)b * Mn + m0 + ml) * 64 + fq);
        union { uint2 u; ushort h[4]; } s;
        s.h[0] = f2h(a.x); s.h[1] = f2h(a.y); s.h[2] = f2h(a.z); s.h[3] = f2h(a.w);
        *(uint2*)(x0h + (size_t)(m0 + ml) * Cn + b * 64 + fq) = s.u;
    }
}

__device__ __forceinline__ void wfrag_block(const float* __restrict__ W,
                                            ushort* __restrict__ wfrag, int bb, int t) {
    int idx = bb * 256 + t;
    if (idx < 12 * 4 * 64 * 8) {
        int j    = idx & 7;
        int lane = (idx >> 3) & 63;
        int n    = (idx >> 9) & 3;
        int kk   = idx >> 11;
        int k    = (lane >> 4) * 8 + j;
        int lev  = kk >> 1;
        int f    = (kk & 1) * 32 + k;
        int fo   = n * 16 + (lane & 15);
        wfrag[idx] = f2h(W[(f * Kn + lev) * FOUTn + fo]);
    }
}

// ---------------- primary: direct padded-CSR build + wfrag + transpose ----------
// No hist, no scan: slot = atomicAdd(cnt[r]) indexes directly into the padded
// row block. Pad pre-zeroed by the memset -> unused slots are (col 0, w 0).

__global__ __launch_bounds__(256) void k_build_aux(const int* __restrict__ rows,
                                                   const int* __restrict__ cols,
                                                   const float* __restrict__ vals,
                                                   int* __restrict__ cnt,
                                                   int2* __restrict__ csr_pad,
                                                   const float* __restrict__ W,
                                                   ushort* __restrict__ wfrag,
                                                   const float* __restrict__ x,
                                                   ushort* __restrict__ x0h) {
    int bb = blockIdx.x;
    if (bb < SCGRID) {
        int e = bb * 256 + threadIdx.x;
        if (e < NNZn) {
            int r = rows[e];
            int s = atomicAdd(&cnt[r], 1);
            if (s < PADW) {
                int2 cv; cv.x = cols[e]; cv.y = __float_as_int(vals[e]);
                csr_pad[(size_t)r * PADW + s] = cv;
            }
        }
        return;
    }
    bb -= SCGRID;
    if (bb < WFGRID) { wfrag_block(W, wfrag, bb, threadIdx.x); return; }
    bb -= WFGRID;
    transpose_block(x, x0h, bb * 4, threadIdx.x);
}

// ---------------- SpMM: dual-row per wave, padded CSR (doubled MLP) -----------
// R13 counters: 60us, VALU 21%, occ 41%, 3.9 TB/s -- Little's law says the
// limit is per-wave outstanding gathers (8 = row degree). This kernel gives
// each wave TWO rows, interleaving their 8-deep batches -> 16 independent 1KB
// gathers in flight, same bytes/instruction (R9/R10's failure was trading
// bytes/instr or VALU for locality; this trades neither). Zero-padded slots
// (col 0, w 0) let both rows run to max(degA,degB) with no masking and no
// clamps. launch_bounds(256,3) gives regalloc room (~168 VGPR) so the loads
// aren't sunk (R4/R5 lesson).

__global__ __launch_bounds__(256, 3) void k_spmm_pd(const ushort* __restrict__ xc,
                                                    const ushort* __restrict__ xp,
                                                    ushort* __restrict__ xn,
                                                    const int* __restrict__ cnt,
                                                    const int2* __restrict__ csr_pad,
                                                    int first) {
    int t = threadIdx.x;
    int lane = t & 63;
    int wv = t >> 6;
    int mA = blockIdx.x * 8 + wv * 2;
    int mB = mA + 1;
    const uint4* xc4 = (const uint4*)xc;

    uint4 vA = xc4[(size_t)mA * 64 + lane];
    uint4 vB = xc4[(size_t)mB * 64 + lane];
    uint4 pA, pB;
    if (!first) {
        pA = ((const uint4*)xp)[(size_t)mA * 64 + lane];
        pB = ((const uint4*)xp)[(size_t)mB * 64 + lane];
    }
    int dA = cnt[mA]; dA = (dA < PADW) ? dA : PADW;
    int dB = cnt[mB]; dB = (dB < PADW) ? dB : PADW;
    int maxd = (dA > dB) ? dA : dB;

    float aA[8], aB[8];
    { union { uint4 u; _Float16 h[8]; } c; c.u = vA;
#pragma unroll
      for (int i = 0; i < 8; ++i) aA[i] = -(float)c.h[i]; }
    { union { uint4 u; _Float16 h[8]; } c; c.u = vB;
#pragma unroll
      for (int i = 0; i < 8; ++i) aB[i] = -(float)c.h[i]; }

    const int2* ceA = csr_pad + (size_t)mA * PADW;
    const int2* ceB = csr_pad + (size_t)mB * PADW;

    for (int i = 0; i < maxd; i += 8) {     // padded: slots < 32, batch reads safe
        int2 cA[8], cB[8];
#pragma unroll
        for (int k = 0; k < 8; ++k) { cA[k] = ceA[i + k]; cB[k] = ceB[i + k]; }
        uint4 gA[8], gB[8];
#pragma unroll
        for (int k = 0; k < 8; ++k) {
            gA[k] = xc4[(size_t)cA[k].x * 64 + lane];
            gB[k] = xc4[(size_t)cB[k].x * 64 + lane];
        }
#pragma unroll
        for (int k = 0; k < 8; ++k) {
            fmah8(aA, gA[k], __int_as_float(cA[k].y));
            fmah8(aB, gB[k], __int_as_float(cB[k].y));
        }
    }

    if (!first) {
        union { uint4 u; _Float16 h[8]; } c;
        c.u = pA;
#pragma unroll
        for (int i = 0; i < 8; ++i) aA[i] = 2.f * aA[i] - (float)c.h[i];
        c.u = pB;
#pragma unroll
        for (int i = 0; i < 8; ++i) aB[i] = 2.f * aB[i] - (float)c.h[i];
    }
    union { uint4 u; _Float16 h[8]; } sA, sB;
#pragma unroll
    for (int i = 0; i < 8; ++i) { sA.h[i] = (_Float16)aA[i]; sB.h[i] = (_Float16)aB[i]; }
    ((uint4*)xn)[(size_t)mA * 64 + lane] = sA.u;
    ((uint4*)xn)[(size_t)mB * 64 + lane] = sB.u;
}

// ---------------- fallback CSR-build kernels (R11-verified sequence) ----------

__global__ __launch_bounds__(256) void k_hist(const int* __restrict__ rows,
                                              int* __restrict__ cnt) {
    int e = blockIdx.x * 256 + threadIdx.x;
    if (e < NNZn) atomicAdd(&cnt[rows[e]], 1);
}

__global__ __launch_bounds__(256) void k_scan_part(const int* __restrict__ cnt,
                                                   int* __restrict__ rowptr,
                                                   int* __restrict__ bsum) {
    __shared__ int part[256];
    int tid = threadIdx.x;
    int r = blockIdx.x * 256 + tid;
    int v = (r < Mn) ? cnt[r] : 0;
    part[tid] = v;
    __syncthreads();
    for (int off = 1; off < 256; off <<= 1) {
        int t = (tid >= off) ? part[tid - off] : 0;
        __syncthreads();
        part[tid] += t;
        __syncthreads();
    }
    if (r < Mn) rowptr[r] = part[tid] - v;
    if (tid == 255) bsum[blockIdx.x] = part[255];
}

__global__ __launch_bounds__(256) void k_scan_add2(int* __restrict__ rowptr,
                                                   const int* __restrict__ bsum,
                                                   int* __restrict__ wcur) {
    __shared__ int part[256];
    int tid = threadIdx.x;
    int v = (tid < NB) ? bsum[tid] : 0;
    part[tid] = v;
    __syncthreads();
    for (int off = 1; off < 256; off <<= 1) {
        int t = (tid >= off) ? part[tid - off] : 0;
        __syncthreads();
        part[tid] += t;
        __syncthreads();
    }
    __shared__ int boff_s, total_s;
    if (tid == 0) {
        boff_s = part[blockIdx.x] - bsum[blockIdx.x];
        total_s = part[NB - 1];
    }
    __syncthreads();
    int r = blockIdx.x * 256 + tid;
    if (r < Mn) {
        int val = rowptr[r] + boff_s;
        rowptr[r] = val;
        wcur[r] = val;
    }
    if (blockIdx.x == 0 && tid == 0) rowptr[Mn] = total_s;
}

__global__ __launch_bounds__(256) void k_fused_aux(const int* __restrict__ rows,
                                                   const int* __restrict__ cols,
                                                   const float* __restrict__ vals,
                                                   int* __restrict__ wcur,
                                                   int2* __restrict__ csr,
                                                   const float* __restrict__ W,
                                                   ushort* __restrict__ wfrag,
                                                   const float* __restrict__ x,
                                                   ushort* __restrict__ x0h) {
    int bb = blockIdx.x;
    if (bb < SCGRID) {
        int e = bb * 256 + threadIdx.x;
        if (e < NNZn) {
            int p = atomicAdd(&wcur[rows[e]], 1);
            int2 cv; cv.x = cols[e]; cv.y = __float_as_int(vals[e]);
            csr[p] = cv;
        }
        return;
    }
    bb -= SCGRID;
    if (bb < WFGRID) { wfrag_block(W, wfrag, bb, threadIdx.x); return; }
    bb -= WFGRID;
    transpose_block(x, x0h, bb * 4, threadIdx.x);
}

__global__ __launch_bounds__(256) void k_spmm_h(const ushort* __restrict__ xc,
                                                const ushort* __restrict__ xp,
                                                ushort* __restrict__ xn,
                                                const int* __restrict__ rowptr,
                                                const int2* __restrict__ csr,
                                                int first) {
    int t = threadIdx.x;
    int lane = t & 63;
    int m = blockIdx.x * 4 + (t >> 6);
    int rp0 = rowptr[m], rp1 = rowptr[m + 1];
    spmm_row(xc, xp, xn, csr + rp0, rp1 - rp0, m, lane, first);
}

// ---------------- MFMA projection GEMM (fp16 inputs, fp32 acc) ----------------
// R8 version (verified): waves split by FO; 12 B-fragments register-resident
// (loaded once); shared A-tile double-buffered via global_load_lds with
// XOR-swizzled source granule; 2 barriers/level; stage(lev+2) after the
// read-done barrier.

__global__ __launch_bounds__(256, 4) void k_gemm_mfma(const ushort* __restrict__ xh,
                                                      const ushort* __restrict__ wfrag,
                                                      float* __restrict__ out) {
    __shared__ __align__(16) ushort As[2][4096];   // [buf][64 rows x 64 halves] = 16KB
    int t     = threadIdx.x;
    int wv    = t >> 6;
    int lane  = t & 63;
    int q     = lane >> 4, r = lane & 15;
    int mtile = blockIdx.x % MT;
    int b     = blockIdx.x / MT;
    int m0    = mtile * 64;
    int swz   = r & 7;

    const size_t lstrideH = (size_t)Mn * Cn;   // level stride in halves

    const ushort* wfb = wfrag + ((size_t)wv * 64 + lane) * 8;   // + kkg*2048
    half8 wf0  = *(const half8*)(wfb);
    half8 wf1  = *(const half8*)(wfb + 1 * 2048);
    half8 wf2  = *(const half8*)(wfb + 2 * 2048);
    half8 wf3  = *(const half8*)(wfb + 3 * 2048);
    half8 wf4  = *(const half8*)(wfb + 4 * 2048);
    half8 wf5  = *(const half8*)(wfb + 5 * 2048);
    half8 wf6  = *(const half8*)(wfb + 6 * 2048);
    half8 wf7  = *(const half8*)(wfb + 7 * 2048);
    half8 wf8  = *(const half8*)(wfb + 8 * 2048);
    half8 wf9  = *(const half8*)(wfb + 9 * 2048);
    half8 wf10 = *(const half8*)(wfb + 10 * 2048);
    half8 wf11 = *(const half8*)(wfb + 11 * 2048);

    int srow = wv * 8 + (lane >> 3);
    int gsw  = (lane & 7) ^ (srow & 7);        // (srow+32)&7 == srow&7
    const ushort* gsA = xh + (size_t)(m0 + srow) * Cn + b * 64 + gsw * 8;
    const ushort* gsB = gsA + 32 * (size_t)Cn;

    floatx4 acc0 = (floatx4)0.f, acc1 = (floatx4)0.f;
    floatx4 acc2 = (floatx4)0.f, acc3 = (floatx4)0.f;

#define STAGE(lev, buf) do {                                          \
        gl_lds16(gsA + (size_t)(lev) * lstrideH, &As[buf][wv * 512]); \
        gl_lds16(gsB + (size_t)(lev) * lstrideH, &As[buf][2048 + wv * 512]); \
    } while (0)

#define AF(buf, sub, half) \
    (*(const half8*)&As[buf][((sub) * 16 + r) * 64 + (((((half) * 4) + q) ^ swz) << 3)])

#define LEVEL(lev, buf, VMSTR, WFA, WFB) do {                                         \
        asm volatile("s_waitcnt vmcnt(" VMSTR ")" ::: "memory");                      \
        __syncthreads();                                                              \
        half8 a00 = AF(buf, 0, 0); half8 a10 = AF(buf, 1, 0);                         \
        half8 a20 = AF(buf, 2, 0); half8 a30 = AF(buf, 3, 0);                         \
        half8 a01 = AF(buf, 0, 1); half8 a11 = AF(buf, 1, 1);                         \
        half8 a21 = AF(buf, 2, 1); half8 a31 = AF(buf, 3, 1);                         \
        acc0 = __builtin_amdgcn_mfma_f32_16x16x32_f16(a00, WFA, acc0, 0, 0, 0);       \
        acc1 = __builtin_amdgcn_mfma_f32_16x16x32_f16(a10, WFA, acc1, 0, 0, 0);       \
        acc2 = __builtin_amdgcn_mfma_f32_16x16x32_f16(a20, WFA, acc2, 0, 0, 0);       \
        acc3 = __builtin_amdgcn_mfma_f32_16x16x32_f16(a30, WFA, acc3, 0, 0, 0);       \
        acc0 = __builtin_amdgcn_mfma_f32_16x16x32_f16(a01, WFB, acc0, 0, 0, 0);       \
        acc1 = __builtin_amdgcn_mfma_f32_16x16x32_f16(a11, WFB, acc1, 0, 0, 0);       \
        acc2 = __builtin_amdgcn_mfma_f32_16x16x32_f16(a21, WFB, acc2, 0, 0, 0);       \
        acc3 = __builtin_amdgcn_mfma_f32_16x16x32_f16(a31, WFB, acc3, 0, 0, 0);       \
        __syncthreads();                                                              \
        if ((lev) < 4) STAGE((lev) + 2, buf);                                         \
    } while (0)

    STAGE(0, 0);
    STAGE(1, 1);
    LEVEL(0, 0, "2", wf0,  wf1);
    LEVEL(1, 1, "2", wf2,  wf3);
    LEVEL(2, 0, "2", wf4,  wf5);
    LEVEL(3, 1, "2", wf6,  wf7);
    LEVEL(4, 0, "2", wf8,  wf9);
    LEVEL(5, 1, "0", wf10, wf11);

#undef LEVEL
#undef AF
#undef STAGE

#pragma unroll
    for (int sub = 0; sub < 4; ++sub) {
        floatx4 av = (sub == 0) ? acc0 : (sub == 1) ? acc1 : (sub == 2) ? acc2 : acc3;
#pragma unroll
        for (int reg = 0; reg < 4; ++reg) {
            size_t o = ((size_t)b * Mn + m0 + sub * 16 + q * 4 + reg) * FOUTn
                     + wv * 16 + r;
            out[o] = av[reg];
        }
    }
}

// ---------------- fallback fp32 kernels (ws too small; not expected) ----------------

__global__ __launch_bounds__(512) void k_transpose_f(const float* __restrict__ x,
                                                     float* __restrict__ x0) {
    int m = blockIdx.x, t = threadIdx.x;
    int b = t >> 6, f = t & 63;
    x0[(size_t)m * Cn + t] = x[((size_t)b * Mn + m) * 64 + f];
}

__global__ __launch_bounds__(256) void k_scatter(const int* __restrict__ rows,
                                                 const int* __restrict__ cols,
                                                 const float* __restrict__ vals,
                                                 int* __restrict__ wcur,
                                                 int2* __restrict__ csr) {
    int e = blockIdx.x * 256 + threadIdx.x;
    if (e < NNZn) {
        int p = atomicAdd(&wcur[rows[e]], 1);
        int2 cv; cv.x = cols[e]; cv.y = __float_as_int(vals[e]);
        csr[p] = cv;
    }
}

__global__ __launch_bounds__(256) void k_spmm_f32(const float4* __restrict__ xc,
                                                  const float4* __restrict__ xp,
                                                  float4* __restrict__ xn,
                                                  const int* __restrict__ rowptr,
                                                  const int2* __restrict__ csr,
                                                  int first) {
    int t = threadIdx.x;
    int lane = t & 63;
    int m = blockIdx.x * 4 + (t >> 6);
    size_t rb = (size_t)m * 128;
    float4 v0 = xc[rb + lane];
    float4 v1 = xc[rb + 64 + lane];
    float4 a0 = make_float4(-v0.x, -v0.y, -v0.z, -v0.w);
    float4 a1 = make_float4(-v1.x, -v1.y, -v1.z, -v1.w);
    int e = rowptr[m], end = rowptr[m + 1];
    for (; e < end; ++e) {
        int2 cv = csr[e];
        float w = __int_as_float(cv.y);
        const float4* r = xc + (size_t)cv.x * 128;
        float4 g0 = r[lane], g1 = r[64 + lane];
        a0.x += w * g0.x; a0.y += w * g0.y; a0.z += w * g0.z; a0.w += w * g0.w;
        a1.x += w * g1.x; a1.y += w * g1.y; a1.z += w * g1.z; a1.w += w * g1.w;
    }
    if (!first) {
        float4 p0 = xp[rb + lane];
        float4 p1 = xp[rb + 64 + lane];
        a0.x = 2.f * a0.x - p0.x; a0.y = 2.f * a0.y - p0.y;
        a0.z = 2.f * a0.z - p0.z; a0.w = 2.f * a0.w - p0.w;
        a1.x = 2.f * a1.x - p1.x; a1.y = 2.f * a1.y - p1.y;
        a1.z = 2.f * a1.z - p1.z; a1.w = 2.f * a1.w - p1.w;
    }
    xn[rb + lane] = a0;
    xn[rb + 64 + lane] = a1;
}

__global__ __launch_bounds__(256) void k_gemm2(const float* __restrict__ xa,
                                               const float* __restrict__ xb,
                                               const float* __restrict__ W,
                                               float* __restrict__ out,
                                               int ka, int kb, int accum) {
    __shared__ __align__(16) float Wa[64 * 64];
    __shared__ __align__(16) float Wb[64 * 64];
    __shared__ __align__(16) float xsa[4 * Cn];
    __shared__ __align__(16) float xsb[4 * Cn];
    int t = threadIdx.x;
    size_t m0 = (size_t)blockIdx.x * 4;
    for (int i = t; i < 4096; i += 256) {
        int f = i >> 6, fo = i & 63;
        Wa[i] = W[(f * Kn + ka) * FOUTn + fo];
        Wb[i] = W[(f * Kn + kb) * FOUTn + fo];
    }
    for (int i = t; i < 4 * Cn; i += 256) {
        xsa[i] = xa[m0 * Cn + i];
        xsb[i] = xb[m0 * Cn + i];
    }
    __syncthreads();
    int fo  = (t & 15) * 4;
    int idx = t >> 4;
    int m   = idx & 3;
    int bq  = idx >> 2;
    float4 acc0 = make_float4(0.f, 0.f, 0.f, 0.f);
    float4 acc1 = make_float4(0.f, 0.f, 0.f, 0.f);
    for (int f = 0; f < 64; ++f) {
        float4 wa = *(const float4*)&Wa[f * 64 + fo];
        float a0 = xsa[m * Cn + bq * 64 + f];
        float a1 = xsa[m * Cn + (bq + 4) * 64 + f];
        acc0.x += a0 * wa.x; acc0.y += a0 * wa.y; acc0.z += a0 * wa.z; acc0.w += a0 * wa.w;
        acc1.x += a1 * wa.x; acc1.y += a1 * wa.y; acc1.z += a1 * wa.z; acc1.w += a1 * wa.w;
        float4 wb = *(const float4*)&Wb[f * 64 + fo];
        float b0 = xsb[m * Cn + bq * 64 + f];
        float b1 = xsb[m * Cn + (bq + 4) * 64 + f];
        acc0.x += b0 * wb.x; acc0.y += b0 * wb.y; acc0.z += b0 * wb.z; acc0.w += b0 * wb.w;
        acc1.x += b1 * wb.x; acc1.y += b1 * wb.y; acc1.z += b1 * wb.z; acc1.w += b1 * wb.w;
    }
    size_t o0 = (((size_t)bq * Mn) + (m0 + m)) * FOUTn + fo;
    size_t o1 = (((size_t)(bq + 4) * Mn) + (m0 + m)) * FOUTn + fo;
    float4* out4_0 = (float4*)&out[o0];
    float4* out4_1 = (float4*)&out[o1];
    if (accum) {
        float4 c0 = *out4_0, c1 = *out4_1;
        acc0.x += c0.x; acc0.y += c0.y; acc0.z += c0.z; acc0.w += c0.w;
        acc1.x += c1.x; acc1.y += c1.y; acc1.z += c1.z; acc1.w += c1.w;
    }
    *out4_0 = acc0;
    *out4_1 = acc1;
}

// ---------------- launch ----------------

extern "C" void kernel_launch(void* const* d_in, const int* in_sizes, int n_in,
                              void* d_out, int out_size, void* d_ws, size_t ws_size,
                              hipStream_t stream) {
    const float* x         = (const float*)d_in[0];
    const float* edge_vals = (const float*)d_in[1];
    const float* W         = (const float*)d_in[2];
    const int*   edge_rows = (const int*)d_in[3];
    const int*   edge_cols = (const int*)d_in[4];
    float* out = (float*)d_out;

    char* ws = (char*)d_ws;
    const size_t bufB = (size_t)Mn * Cn * sizeof(float);   // 81.92 MB fp32 level
    const size_t bufH = (size_t)Mn * Cn * sizeof(ushort);  // 40.96 MB fp16 level
    const size_t wfB  = 12 * 4 * 64 * 8 * sizeof(ushort);  // 48 KB
    const size_t csrB = (size_t)(Mn + 4 + Mn) * 4 + (size_t)NNZn * 8;  // ~2.9 MB (packed)
    const size_t padB = (size_t)Mn * 4 + (size_t)Mn * PADW * 8;        // 10.4 MB (padded)

    const int spmm_grid  = Mn / 4;     // 10000 (fallback, 1 row/wave)
    const int spmm_grid2 = Mn / 8;     // 5000  (primary, 2 rows/wave)
    const int gemm_grid  = MT * 8;     // 5000, b-major

    if (ws_size >= 6 * bufH + wfB + padB) {
        // ---- primary: padded CSR + dual-row SpMM, 8 graph nodes ----
        ushort* xh  = (ushort*)ws;                       // slot l at xh + l*Mn*Cn
        ushort* wfr = (ushort*)(ws + 6 * bufH);
        int*    cnt = (int*)(ws + 6 * bufH + wfB);
        int2*   csr_pad = (int2*)(cnt + Mn);
        ushort* slot[6];
        for (int l = 0; l < 6; ++l) slot[l] = xh + (size_t)l * Mn * Cn;

        // one memset zeroes cnt AND the padded edge array (contiguous)
        hipMemsetAsync(cnt, 0, (size_t)Mn * 4 + (size_t)Mn * PADW * 8, stream);
        k_build_aux<<<SCGRID + WFGRID + TGRID, 256, 0, stream>>>(
            edge_rows, edge_cols, edge_vals, cnt, csr_pad, W, wfr, x, slot[0]);

        k_spmm_pd<<<spmm_grid2, 256, 0, stream>>>(slot[0], slot[0], slot[1],
                                                  cnt, csr_pad, 1);
        k_spmm_pd<<<spmm_grid2, 256, 0, stream>>>(slot[1], slot[0], slot[2],
                                                  cnt, csr_pad, 0);
        k_spmm_pd<<<spmm_grid2, 256, 0, stream>>>(slot[2], slot[1], slot[3],
                                                  cnt, csr_pad, 0);
        k_spmm_pd<<<spmm_grid2, 256, 0, stream>>>(slot[3], slot[2], slot[4],
                                                  cnt, csr_pad, 0);
        k_spmm_pd<<<spmm_grid2, 256, 0, stream>>>(slot[4], slot[3], slot[5],
                                                  cnt, csr_pad, 0);
        k_gemm_mfma<<<gemm_grid, 256, 0, stream>>>(xh, wfr, out);
    } else if (ws_size >= 6 * bufH + wfB + csrB) {
        // ---- R11-verified fallback: packed CSR, 10 graph nodes ----
        ushort* xh  = (ushort*)ws;
        ushort* wfr = (ushort*)(ws + 6 * bufH);
        int*    rowptr = (int*)(ws + 6 * bufH + wfB);
        int*    fill   = rowptr + (Mn + 4);              // doubles as wcur
        int2*   csr    = (int2*)(fill + Mn);
        int*    bsum   = (int*)csr;                      // scan scratch in csr buf
        ushort* slot[6];
        for (int l = 0; l < 6; ++l) slot[l] = xh + (size_t)l * Mn * Cn;

        hipMemsetAsync(fill, 0, Mn * sizeof(int), stream);
        k_hist<<<HGRID, 256, 0, stream>>>(edge_rows, fill);
        k_scan_part<<<NB, 256, 0, stream>>>(fill, rowptr, bsum);
        k_scan_add2<<<NB, 256, 0, stream>>>(rowptr, bsum, fill);
        k_fused_aux<<<SCGRID + WFGRID + TGRID, 256, 0, stream>>>(
            edge_rows, edge_cols, edge_vals, fill, csr, W, wfr, x, slot[0]);
        k_spmm_h<<<spmm_grid, 256, 0, stream>>>(slot[0], slot[0], slot[1],
                                                rowptr, csr, 1);
        k_spmm_h<<<spmm_grid, 256, 0, stream>>>(slot[1], slot[0], slot[2],
                                                rowptr, csr, 0);
        k_spmm_h<<<spmm_grid, 256, 0, stream>>>(slot[2], slot[1], slot[3],
                                                rowptr, csr, 0);
        k_spmm_h<<<spmm_grid, 256, 0, stream>>>(slot[3], slot[2], slot[4],
                                                rowptr, csr, 0);
        k_spmm_h<<<spmm_grid, 256, 0, stream>>>(slot[4], slot[3], slot[5],
                                                rowptr, csr, 0);
        k_gemm_mfma<<<gemm_grid, 256, 0, stream>>>(xh, wfr, out);
    } else {
        // fp32 fallback: 3 rotating fp32 buffers + fp32 vector GEMM
        float* buf0 = (float*)(ws);
        float* buf1 = (float*)(ws + bufB);
        float* buf2 = (float*)(ws + 2 * bufB);
        int*   rowptr = (int*)(ws + 3 * bufB);
        int*   fill   = rowptr + (Mn + 4);
        int2*  csr    = (int2*)(fill + Mn);
        int*   bsum   = (int*)csr;
        hipMemsetAsync(fill, 0, Mn * sizeof(int), stream);
        k_hist<<<HGRID, 256, 0, stream>>>(edge_rows, fill);
        k_scan_part<<<NB, 256, 0, stream>>>(fill, rowptr, bsum);
        k_scan_add2<<<NB, 256, 0, stream>>>(rowptr, bsum, fill);
        k_scatter<<<SCGRID, 256, 0, stream>>>(edge_rows, edge_cols,
                                              edge_vals, fill, csr);
        k_transpose_f<<<Mn, 512, 0, stream>>>(x, buf0);
        k_spmm_f32<<<Mn / 4, 256, 0, stream>>>((const float4*)buf0, (const float4*)buf0,
                                               (float4*)buf1, rowptr, csr, 1);
        k_gemm2<<<Mn / 4, 256, 0, stream>>>(buf0, buf1, W, out, 0, 1, 0);
        k_spmm_f32<<<Mn / 4, 256, 0, stream>>>((const float4*)buf1, (const float4*)buf0,
                                               (float4*)buf2, rowptr, csr, 0);
        k_spmm_f32<<<Mn / 4, 256, 0, stream>>>((const float4*)buf2, (const float4*)buf1,
                                               (float4*)buf0, rowptr, csr, 0);
        k_gemm2<<<Mn / 4, 256, 0, stream>>>(buf2, buf0, W, out, 2, 3, 1);
        k_spmm_f32<<<Mn / 4, 256, 0, stream>>>((const float4*)buf0, (const float4*)buf2,
                                               (float4*)buf1, rowptr, csr, 0);
        k_spmm_f32<<<Mn / 4, 256, 0, stream>>>((const float4*)buf1, (const float4*)buf0,
                                               (float4*)buf2, rowptr, csr, 0);
        k_gemm2<<<Mn / 4, 256, 0, stream>>>(buf1, buf2, W, out, 4, 5, 1);
    }
}

// Round 15
// 498.312 us; speedup vs baseline: 1.2396x; 1.2396x over previous
//
#include <hip/hip_runtime.h>

// Problem constants (MeshConv: B=8, M=40000, FIN=64, K=6, FOUT=64, NNZ=320000)
#define Mn    40000
#define Bn    8
#define FINn  64
#define Kn    6
#define FOUTn 64
#define NNZn  320000
#define Cn    512   // FIN*B values per level row; c = b*64 + f
#define NB    ((Mn + 255) / 256)     // scan blocks = 157 (fallback path)
#define MT    (Mn / 64)              // 625 m-tiles for the GEMM
#define HGRID ((NNZn + 255) / 256)   // hist blocks = 1250 (fallback)
#define SCGRID ((NNZn + 255) / 256)  // scatter blocks = 1250
#define WFGRID 96                    // wfrag blocks
#define TGRID  (Mn / 4)              // transpose blocks = 10000
#define PADW  32                     // padded-CSR slots/row (R13-verified: max deg <= 32)

// Level layout (fp16): xh[lev][m][c] -- one row = 1KB contiguous.
// SpMM gathers one full 1KB row per edge (64 lanes x 16B, fully coalesced).

typedef _Float16 half8 __attribute__((ext_vector_type(8)));  // MFMA A/B frag
typedef __attribute__((ext_vector_type(4))) float floatx4;   // MFMA accumulator

__device__ __forceinline__ ushort f2h(float f) {
    _Float16 h = (_Float16)f;
    return *(ushort*)&h;
}

// async global->LDS, 16B per lane; dst must be wave-uniform base (HW adds lane*16)
__device__ __forceinline__ void gl_lds16(const ushort* g, ushort* l) {
    __builtin_amdgcn_global_load_lds(
        (const __attribute__((address_space(1))) unsigned int*)g,
        (__attribute__((address_space(3))) unsigned int*)l, 16, 0, 0);
}

// ---------------- shared device bodies ----------------

__device__ __forceinline__ void fmah8(float* a, uint4 g, float w) {
    union { uint4 u; _Float16 h[8]; } c; c.u = g;
#pragma unroll
    for (int i = 0; i < 8; ++i) a[i] += w * (float)c.h[i];
}

// R8-proven SpMM row body (fallback packed-CSR path).
__device__ __forceinline__ void spmm_row(const ushort* __restrict__ xc,
                                         const ushort* __restrict__ xp,
                                         ushort* __restrict__ xn,
                                         const int2* __restrict__ ce, int deg,
                                         int m, int lane, int first) {
    const uint4* xc4 = (const uint4*)xc;      // row = 64 uint4 (512 halves)
    uint4 v = xc4[(size_t)m * 64 + lane];
    uint4 p;
    if (!first) p = ((const uint4*)xp)[(size_t)m * 64 + lane];   // early issue
    float a[8];
    { union { uint4 u; _Float16 h[8]; } c; c.u = v;
#pragma unroll
      for (int i = 0; i < 8; ++i) a[i] = -(float)c.h[i]; }

    int i = 0;
    for (; i + 8 <= deg; i += 8) {
        int2 cv[8];
#pragma unroll
        for (int k = 0; k < 8; ++k) cv[k] = ce[i + k];
        uint4 g[8];
#pragma unroll
        for (int k = 0; k < 8; ++k) g[k] = xc4[(size_t)cv[k].x * 64 + lane];
#pragma unroll
        for (int k = 0; k < 8; ++k) fmah8(a, g[k], __int_as_float(cv[k].y));
    }
    for (; i + 4 <= deg; i += 4) {
        int2 cv0 = ce[i],     cv1 = ce[i + 1];
        int2 cv2 = ce[i + 2], cv3 = ce[i + 3];
        uint4 g0 = xc4[(size_t)cv0.x * 64 + lane];
        uint4 g1 = xc4[(size_t)cv1.x * 64 + lane];
        uint4 g2 = xc4[(size_t)cv2.x * 64 + lane];
        uint4 g3 = xc4[(size_t)cv3.x * 64 + lane];
        fmah8(a, g0, __int_as_float(cv0.y));
        fmah8(a, g1, __int_as_float(cv1.y));
        fmah8(a, g2, __int_as_float(cv2.y));
        fmah8(a, g3, __int_as_float(cv3.y));
    }
    for (; i < deg; ++i) {
        int2 cv = ce[i];
        uint4 g = xc4[(size_t)cv.x * 64 + lane];
        fmah8(a, g, __int_as_float(cv.y));
    }

    if (!first) {
        union { uint4 u; _Float16 h[8]; } c; c.u = p;
#pragma unroll
        for (int i2 = 0; i2 < 8; ++i2) a[i2] = 2.f * a[i2] - (float)c.h[i2];
    }
    union { uint4 u; _Float16 h[8]; } s;
#pragma unroll
    for (int i2 = 0; i2 < 8; ++i2) s.h[i2] = (_Float16)a[i2];
    ((uint4*)xn)[(size_t)m * 64 + lane] = s.u;
}

__device__ __forceinline__ void transpose_block(const float* __restrict__ x,
                                                ushort* __restrict__ x0h, int m0, int t) {
#pragma unroll
    for (int k = 0; k < 2; ++k) {
        int i   = t + k * 256;       // 0..511
        int ml  = i >> 7;            // 0..3
        int rem = i & 127;
        int b   = rem >> 4;
        int fq  = (rem & 15) * 4;
        float4 a = *(const float4*)(x + ((size_t)b * Mn + m0 + ml) * 64 + fq);
        union { uint2 u; ushort h[4]; } s;
        s.h[0] = f2h(a.x); s.h[1] = f2h(a.y); s.h[2] = f2h(a.z); s.h[3] = f2h(a.w);
        *(uint2*)(x0h + (size_t)(m0 + ml) * Cn + b * 64 + fq) = s.u;
    }
}

__device__ __forceinline__ void wfrag_block(const float* __restrict__ W,
                                            ushort* __restrict__ wfrag, int bb, int t) {
    int idx = bb * 256 + t;
    if (idx < 12 * 4 * 64 * 8) {
        int j    = idx & 7;
        int lane = (idx >> 3) & 63;
        int n    = (idx >> 9) & 3;
        int kk   = idx >> 11;
        int k    = (lane >> 4) * 8 + j;
        int lev  = kk >> 1;
        int f    = (kk & 1) * 32 + k;
        int fo   = n * 16 + (lane & 15);
        wfrag[idx] = f2h(W[(f * Kn + lev) * FOUTn + fo]);
    }
}

// ---------------- primary: direct padded-CSR build + wfrag + transpose ----------
// No hist, no scan: slot = atomicAdd(cnt[r]) indexes directly into the padded
// row block. Pad pre-zeroed by the memset -> unused slots are (col 0, w 0),
// which makes unconditional batch-0 reads safe in the SpMM.

__global__ __launch_bounds__(256) void k_build_aux(const int* __restrict__ rows,
                                                   const int* __restrict__ cols,
                                                   const float* __restrict__ vals,
                                                   int* __restrict__ cnt,
                                                   int2* __restrict__ csr_pad,
                                                   const float* __restrict__ W,
                                                   ushort* __restrict__ wfrag,
                                                   const float* __restrict__ x,
                                                   ushort* __restrict__ x0h) {
    int bb = blockIdx.x;
    if (bb < SCGRID) {
        int e = bb * 256 + threadIdx.x;
        if (e < NNZn) {
            int r = rows[e];
            int s = atomicAdd(&cnt[r], 1);
            if (s < PADW) {
                int2 cv; cv.x = cols[e]; cv.y = __float_as_int(vals[e]);
                csr_pad[(size_t)r * PADW + s] = cv;
            }
        }
        return;
    }
    bb -= SCGRID;
    if (bb < WFGRID) { wfrag_block(W, wfrag, bb, threadIdx.x); return; }
    bb -= WFGRID;
    transpose_block(x, x0h, bb * 4, threadIdx.x);
}

// ---------------- SpMM: padded CSR, dependency-shortened (R13 structure) -------
// R13 critical path per wave: cnt[m] -> csr batch -> gathers (three serial
// memory hops). With the ZERO-FILLED pad, batch 0's 8 csr slots are readable
// unconditionally at kernel entry (zero weight => zero contribution; col 0 =>
// one hot line). So v, p, csr[0..8), and cnt[m] all issue back-to-back and
// batch-0 gathers wait only on the csr slots: one serial hop removed from
// every wave. Structure otherwise identical to R13's verified 60us kernel
// (1 row/wave, 1KB gathers, 8-deep). Cost: ~1 zero-FMA edge per row.

__global__ __launch_bounds__(256) void k_spmm_p(const ushort* __restrict__ xc,
                                                const ushort* __restrict__ xp,
                                                ushort* __restrict__ xn,
                                                const int* __restrict__ cnt,
                                                const int2* __restrict__ csr_pad,
                                                int first) {
    int t = threadIdx.x;
    int lane = t & 63;
    int m = blockIdx.x * 4 + (t >> 6);
    const uint4* xc4 = (const uint4*)xc;
    const int2* ce = csr_pad + (size_t)m * PADW;

    // all independent loads issued back-to-back:
    uint4 v = xc4[(size_t)m * 64 + lane];
    uint4 p;
    if (!first) p = ((const uint4*)xp)[(size_t)m * 64 + lane];
    int2 cv[8];
#pragma unroll
    for (int k = 0; k < 8; ++k) cv[k] = ce[k];          // unconditional (padded)
    int deg = cnt[m];
    deg = (deg < PADW) ? deg : PADW;

    // batch-0 gathers depend only on cv
    uint4 g[8];
#pragma unroll
    for (int k = 0; k < 8; ++k) g[k] = xc4[(size_t)cv[k].x * 64 + lane];

    float a[8];
    { union { uint4 u; _Float16 h[8]; } c; c.u = v;
#pragma unroll
      for (int i = 0; i < 8; ++i) a[i] = -(float)c.h[i]; }
#pragma unroll
    for (int k = 0; k < 8; ++k) fmah8(a, g[k], __int_as_float(cv[k].y));

    // remaining batches (deg > 8); padded reads up to PADW are safe
    for (int i = 8; i < deg; i += 8) {
        int2 cv2[8];
#pragma unroll
        for (int k = 0; k < 8; ++k) cv2[k] = ce[i + k];
        uint4 g2[8];
#pragma unroll
        for (int k = 0; k < 8; ++k) g2[k] = xc4[(size_t)cv2[k].x * 64 + lane];
#pragma unroll
        for (int k = 0; k < 8; ++k) fmah8(a, g2[k], __int_as_float(cv2[k].y));
    }

    if (!first) {
        union { uint4 u; _Float16 h[8]; } c; c.u = p;
#pragma unroll
        for (int i = 0; i < 8; ++i) a[i] = 2.f * a[i] - (float)c.h[i];
    }
    union { uint4 u; _Float16 h[8]; } s;
#pragma unroll
    for (int i = 0; i < 8; ++i) s.h[i] = (_Float16)a[i];
    ((uint4*)xn)[(size_t)m * 64 + lane] = s.u;
}

// ---------------- fallback CSR-build kernels (R11-verified sequence) ----------

__global__ __launch_bounds__(256) void k_hist(const int* __restrict__ rows,
                                              int* __restrict__ cnt) {
    int e = blockIdx.x * 256 + threadIdx.x;
    if (e < NNZn) atomicAdd(&cnt[rows[e]], 1);
}

__global__ __launch_bounds__(256) void k_scan_part(const int* __restrict__ cnt,
                                                   int* __restrict__ rowptr,
                                                   int* __restrict__ bsum) {
    __shared__ int part[256];
    int tid = threadIdx.x;
    int r = blockIdx.x * 256 + tid;
    int v = (r < Mn) ? cnt[r] : 0;
    part[tid] = v;
    __syncthreads();
    for (int off = 1; off < 256; off <<= 1) {
        int t = (tid >= off) ? part[tid - off] : 0;
        __syncthreads();
        part[tid] += t;
        __syncthreads();
    }
    if (r < Mn) rowptr[r] = part[tid] - v;
    if (tid == 255) bsum[blockIdx.x] = part[255];
}

__global__ __launch_bounds__(256) void k_scan_add2(int* __restrict__ rowptr,
                                                   const int* __restrict__ bsum,
                                                   int* __restrict__ wcur) {
    __shared__ int part[256];
    int tid = threadIdx.x;
    int v = (tid < NB) ? bsum[tid] : 0;
    part[tid] = v;
    __syncthreads();
    for (int off = 1; off < 256; off <<= 1) {
        int t = (tid >= off) ? part[tid - off] : 0;
        __syncthreads();
        part[tid] += t;
        __syncthreads();
    }
    __shared__ int boff_s, total_s;
    if (tid == 0) {
        boff_s = part[blockIdx.x] - bsum[blockIdx.x];
        total_s = part[NB - 1];
    }
    __syncthreads();
    int r = blockIdx.x * 256 + tid;
    if (r < Mn) {
        int val = rowptr[r] + boff_s;
        rowptr[r] = val;
        wcur[r] = val;
    }
    if (blockIdx.x == 0 && tid == 0) rowptr[Mn] = total_s;
}

__global__ __launch_bounds__(256) void k_fused_aux(const int* __restrict__ rows,
                                                   const int* __restrict__ cols,
                                                   const float* __restrict__ vals,
                                                   int* __restrict__ wcur,
                                                   int2* __restrict__ csr,
                                                   const float* __restrict__ W,
                                                   ushort* __restrict__ wfrag,
                                                   const float* __restrict__ x,
                                                   ushort* __restrict__ x0h) {
    int bb = blockIdx.x;
    if (bb < SCGRID) {
        int e = bb * 256 + threadIdx.x;
        if (e < NNZn) {
            int p = atomicAdd(&wcur[rows[e]], 1);
            int2 cv; cv.x = cols[e]; cv.y = __float_as_int(vals[e]);
            csr[p] = cv;
        }
        return;
    }
    bb -= SCGRID;
    if (bb < WFGRID) { wfrag_block(W, wfrag, bb, threadIdx.x); return; }
    bb -= WFGRID;
    transpose_block(x, x0h, bb * 4, threadIdx.x);
}

__global__ __launch_bounds__(256) void k_spmm_h(const ushort* __restrict__ xc,
                                                const ushort* __restrict__ xp,
                                                ushort* __restrict__ xn,
                                                const int* __restrict__ rowptr,
                                                const int2* __restrict__ csr,
                                                int first) {
    int t = threadIdx.x;
    int lane = t & 63;
    int m = blockIdx.x * 4 + (t >> 6);
    int rp0 = rowptr[m], rp1 = rowptr[m + 1];
    spmm_row(xc, xp, xn, csr + rp0, rp1 - rp0, m, lane, first);
}

// ---------------- MFMA projection GEMM (fp16 inputs, fp32 acc) ----------------
// R8 version (verified): waves split by FO; 12 B-fragments register-resident
// (loaded once); shared A-tile double-buffered via global_load_lds with
// XOR-swizzled source granule; 2 barriers/level; stage(lev+2) after the
// read-done barrier.

__global__ __launch_bounds__(256, 4) void k_gemm_mfma(const ushort* __restrict__ xh,
                                                      const ushort* __restrict__ wfrag,
                                                      float* __restrict__ out) {
    __shared__ __align__(16) ushort As[2][4096];   // [buf][64 rows x 64 halves] = 16KB
    int t     = threadIdx.x;
    int wv    = t >> 6;
    int lane  = t & 63;
    int q     = lane >> 4, r = lane & 15;
    int mtile = blockIdx.x % MT;
    int b     = blockIdx.x / MT;
    int m0    = mtile * 64;
    int swz   = r & 7;

    const size_t lstrideH = (size_t)Mn * Cn;   // level stride in halves

    const ushort* wfb = wfrag + ((size_t)wv * 64 + lane) * 8;   // + kkg*2048
    half8 wf0  = *(const half8*)(wfb);
    half8 wf1  = *(const half8*)(wfb + 1 * 2048);
    half8 wf2  = *(const half8*)(wfb + 2 * 2048);
    half8 wf3  = *(const half8*)(wfb + 3 * 2048);
    half8 wf4  = *(const half8*)(wfb + 4 * 2048);
    half8 wf5  = *(const half8*)(wfb + 5 * 2048);
    half8 wf6  = *(const half8*)(wfb + 6 * 2048);
    half8 wf7  = *(const half8*)(wfb + 7 * 2048);
    half8 wf8  = *(const half8*)(wfb + 8 * 2048);
    half8 wf9  = *(const half8*)(wfb + 9 * 2048);
    half8 wf10 = *(const half8*)(wfb + 10 * 2048);
    half8 wf11 = *(const half8*)(wfb + 11 * 2048);

    int srow = wv * 8 + (lane >> 3);
    int gsw  = (lane & 7) ^ (srow & 7);        // (srow+32)&7 == srow&7
    const ushort* gsA = xh + (size_t)(m0 + srow) * Cn + b * 64 + gsw * 8;
    const ushort* gsB = gsA + 32 * (size_t)Cn;

    floatx4 acc0 = (floatx4)0.f, acc1 = (floatx4)0.f;
    floatx4 acc2 = (floatx4)0.f, acc3 = (floatx4)0.f;

#define STAGE(lev, buf) do {                                          \
        gl_lds16(gsA + (size_t)(lev) * lstrideH, &As[buf][wv * 512]); \
        gl_lds16(gsB + (size_t)(lev) * lstrideH, &As[buf][2048 + wv * 512]); \
    } while (0)

#define AF(buf, sub, half) \
    (*(const half8*)&As[buf][((sub) * 16 + r) * 64 + (((((half) * 4) + q) ^ swz) << 3)])

#define LEVEL(lev, buf, VMSTR, WFA, WFB) do {                                         \
        asm volatile("s_waitcnt vmcnt(" VMSTR ")" ::: "memory");                      \
        __syncthreads();                                                              \
        half8 a00 = AF(buf, 0, 0); half8 a10 = AF(buf, 1, 0);                         \
        half8 a20 = AF(buf, 2, 0); half8 a30 = AF(buf, 3, 0);                         \
        half8 a01 = AF(buf, 0, 1); half8 a11 = AF(buf, 1, 1);                         \
        half8 a21 = AF(buf, 2, 1); half8 a31 = AF(buf, 3, 1);                         \
        acc0 = __builtin_amdgcn_mfma_f32_16x16x32_f16(a00, WFA, acc0, 0, 0, 0);       \
        acc1 = __builtin_amdgcn_mfma_f32_16x16x32_f16(a10, WFA, acc1, 0, 0, 0);       \
        acc2 = __builtin_amdgcn_mfma_f32_16x16x32_f16(a20, WFA, acc2, 0, 0, 0);       \
        acc3 = __builtin_amdgcn_mfma_f32_16x16x32_f16(a30, WFA, acc3, 0, 0, 0);       \
        acc0 = __builtin_amdgcn_mfma_f32_16x16x32_f16(a01, WFB, acc0, 0, 0, 0);       \
        acc1 = __builtin_amdgcn_mfma_f32_16x16x32_f16(a11, WFB, acc1, 0, 0, 0);       \
        acc2 = __builtin_amdgcn_mfma_f32_16x16x32_f16(a21, WFB, acc2, 0, 0, 0);       \
        acc3 = __builtin_amdgcn_mfma_f32_16x16x32_f16(a31, WFB, acc3, 0, 0, 0);       \
        __syncthreads();                                                              \
        if ((lev) < 4) STAGE((lev) + 2, buf);                                         \
    } while (0)

    STAGE(0, 0);
    STAGE(1, 1);
    LEVEL(0, 0, "2", wf0,  wf1);
    LEVEL(1, 1, "2", wf2,  wf3);
    LEVEL(2, 0, "2", wf4,  wf5);
    LEVEL(3, 1, "2", wf6,  wf7);
    LEVEL(4, 0, "2", wf8,  wf9);
    LEVEL(5, 1, "0", wf10, wf11);

#undef LEVEL
#undef AF
#undef STAGE

#pragma unroll
    for (int sub = 0; sub < 4; ++sub) {
        floatx4 av = (sub == 0) ? acc0 : (sub == 1) ? acc1 : (sub == 2) ? acc2 : acc3;
#pragma unroll
        for (int reg = 0; reg < 4; ++reg) {
            size_t o = ((size_t)b * Mn + m0 + sub * 16 + q * 4 + reg) * FOUTn
                     + wv * 16 + r;
            out[o] = av[reg];
        }
    }
}

// ---------------- fallback fp32 kernels (ws too small; not expected) ----------------

__global__ __launch_bounds__(512) void k_transpose_f(const float* __restrict__ x,
                                                     float* __restrict__ x0) {
    int m = blockIdx.x, t = threadIdx.x;
    int b = t >> 6, f = t & 63;
    x0[(size_t)m * Cn + t] = x[((size_t)b * Mn + m) * 64 + f];
}

__global__ __launch_bounds__(256) void k_scatter(const int* __restrict__ rows,
                                                 const int* __restrict__ cols,
                                                 const float* __restrict__ vals,
                                                 int* __restrict__ wcur,
                                                 int2* __restrict__ csr) {
    int e = blockIdx.x * 256 + threadIdx.x;
    if (e < NNZn) {
        int p = atomicAdd(&wcur[rows[e]], 1);
        int2 cv; cv.x = cols[e]; cv.y = __float_as_int(vals[e]);
        csr[p] = cv;
    }
}

__global__ __launch_bounds__(256) void k_spmm_f32(const float4* __restrict__ xc,
                                                  const float4* __restrict__ xp,
                                                  float4* __restrict__ xn,
                                                  const int* __restrict__ rowptr,
                                                  const int2* __restrict__ csr,
                                                  int first) {
    int t = threadIdx.x;
    int lane = t & 63;
    int m = blockIdx.x * 4 + (t >> 6);
    size_t rb = (size_t)m * 128;
    float4 v0 = xc[rb + lane];
    float4 v1 = xc[rb + 64 + lane];
    float4 a0 = make_float4(-v0.x, -v0.y, -v0.z, -v0.w);
    float4 a1 = make_float4(-v1.x, -v1.y, -v1.z, -v1.w);
    int e = rowptr[m], end = rowptr[m + 1];
    for (; e < end; ++e) {
        int2 cv = csr[e];
        float w = __int_as_float(cv.y);
        const float4* r = xc + (size_t)cv.x * 128;
        float4 g0 = r[lane], g1 = r[64 + lane];
        a0.x += w * g0.x; a0.y += w * g0.y; a0.z += w * g0.z; a0.w += w * g0.w;
        a1.x += w * g1.x; a1.y += w * g1.y; a1.z += w * g1.z; a1.w += w * g1.w;
    }
    if (!first) {
        float4 p0 = xp[rb + lane];
        float4 p1 = xp[rb + 64 + lane];
        a0.x = 2.f * a0.x - p0.x; a0.y = 2.f * a0.y - p0.y;
        a0.z = 2.f * a0.z - p0.z; a0.w = 2.f * a0.w - p0.w;
        a1.x = 2.f * a1.x - p1.x; a1.y = 2.f * a1.y - p1.y;
        a1.z = 2.f * a1.z - p1.z; a1.w = 2.f * a1.w - p1.w;
    }
    xn[rb + lane] = a0;
    xn[rb + 64 + lane] = a1;
}

__global__ __launch_bounds__(256) void k_gemm2(const float* __restrict__ xa,
                                               const float* __restrict__ xb,
                                               const float* __restrict__ W,
                                               float* __restrict__ out,
                                               int ka, int kb, int accum) {
    __shared__ __align__(16) float Wa[64 * 64];
    __shared__ __align__(16) float Wb[64 * 64];
    __shared__ __align__(16) float xsa[4 * Cn];
    __shared__ __align__(16) float xsb[4 * Cn];
    int t = threadIdx.x;
    size_t m0 = (size_t)blockIdx.x * 4;
    for (int i = t; i < 4096; i += 256) {
        int f = i >> 6, fo = i & 63;
        Wa[i] = W[(f * Kn + ka) * FOUTn + fo];
        Wb[i] = W[(f * Kn + kb) * FOUTn + fo];
    }
    for (int i = t; i < 4 * Cn; i += 256) {
        xsa[i] = xa[m0 * Cn + i];
        xsb[i] = xb[m0 * Cn + i];
    }
    __syncthreads();
    int fo  = (t & 15) * 4;
    int idx = t >> 4;
    int m   = idx & 3;
    int bq  = idx >> 2;
    float4 acc0 = make_float4(0.f, 0.f, 0.f, 0.f);
    float4 acc1 = make_float4(0.f, 0.f, 0.f, 0.f);
    for (int f = 0; f < 64; ++f) {
        float4 wa = *(const float4*)&Wa[f * 64 + fo];
        float a0 = xsa[m * Cn + bq * 64 + f];
        float a1 = xsa[m * Cn + (bq + 4) * 64 + f];
        acc0.x += a0 * wa.x; acc0.y += a0 * wa.y; acc0.z += a0 * wa.z; acc0.w += a0 * wa.w;
        acc1.x += a1 * wa.x; acc1.y += a1 * wa.y; acc1.z += a1 * wa.z; acc1.w += a1 * wa.w;
        float4 wb = *(const float4*)&Wb[f * 64 + fo];
        float b0 = xsb[m * Cn + bq * 64 + f];
        float b1 = xsb[m * Cn + (bq + 4) * 64 + f];
        acc0.x += b0 * wb.x; acc0.y += b0 * wb.y; acc0.z += b0 * wb.z; acc0.w += b0 * wb.w;
        acc1.x += b1 * wb.x; acc1.y += b1 * wb.y; acc1.z += b1 * wb.z; acc1.w += b1 * wb.w;
    }
    size_t o0 = (((size_t)bq * Mn) + (m0 + m)) * FOUTn + fo;
    size_t o1 = (((size_t)(bq + 4) * Mn) + (m0 + m)) * FOUTn + fo;
    float4* out4_0 = (float4*)&out[o0];
    float4* out4_1 = (float4*)&out[o1];
    if (accum) {
        float4 c0 = *out4_0, c1 = *out4_1;
        acc0.x += c0.x; acc0.y += c0.y; acc0.z += c0.z; acc0.w += c0.w;
        acc1.x += c1.x; acc1.y += c1.y; acc1.z += c1.z; acc1.w += c1.w;
    }
    *out4_0 = acc0;
    *out4_1 = acc1;
}

// ---------------- launch ----------------

extern "C" void kernel_launch(void* const* d_in, const int* in_sizes, int n_in,
                              void* d_out, int out_size, void* d_ws, size_t ws_size,
                              hipStream_t stream) {
    const float* x         = (const float*)d_in[0];
    const float* edge_vals = (const float*)d_in[1];
    const float* W         = (const float*)d_in[2];
    const int*   edge_rows = (const int*)d_in[3];
    const int*   edge_cols = (const int*)d_in[4];
    float* out = (float*)d_out;

    char* ws = (char*)d_ws;
    const size_t bufB = (size_t)Mn * Cn * sizeof(float);   // 81.92 MB fp32 level
    const size_t bufH = (size_t)Mn * Cn * sizeof(ushort);  // 40.96 MB fp16 level
    const size_t wfB  = 12 * 4 * 64 * 8 * sizeof(ushort);  // 48 KB
    const size_t csrB = (size_t)(Mn + 4 + Mn) * 4 + (size_t)NNZn * 8;  // ~2.9 MB (packed)
    const size_t padB = (size_t)Mn * 4 + (size_t)Mn * PADW * 8;        // 10.4 MB (padded)

    const int spmm_grid  = Mn / 4;     // 10000 (1 row/wave, both CSR forms)
    const int gemm_grid  = MT * 8;     // 5000, b-major

    if (ws_size >= 6 * bufH + wfB + padB) {
        // ---- primary: padded CSR + dependency-shortened SpMM, 8 graph nodes ----
        ushort* xh  = (ushort*)ws;                       // slot l at xh + l*Mn*Cn
        ushort* wfr = (ushort*)(ws + 6 * bufH);
        int*    cnt = (int*)(ws + 6 * bufH + wfB);
        int2*   csr_pad = (int2*)(cnt + Mn);
        ushort* slot[6];
        for (int l = 0; l < 6; ++l) slot[l] = xh + (size_t)l * Mn * Cn;

        // one memset zeroes cnt AND the padded edge array (contiguous); the
        // zero-filled pad is what makes unconditional batch-0 reads safe
        hipMemsetAsync(cnt, 0, (size_t)Mn * 4 + (size_t)Mn * PADW * 8, stream);
        k_build_aux<<<SCGRID + WFGRID + TGRID, 256, 0, stream>>>(
            edge_rows, edge_cols, edge_vals, cnt, csr_pad, W, wfr, x, slot[0]);

        k_spmm_p<<<spmm_grid, 256, 0, stream>>>(slot[0], slot[0], slot[1],
                                                cnt, csr_pad, 1);
        k_spmm_p<<<spmm_grid, 256, 0, stream>>>(slot[1], slot[0], slot[2],
                                                cnt, csr_pad, 0);
        k_spmm_p<<<spmm_grid, 256, 0, stream>>>(slot[2], slot[1], slot[3],
                                                cnt, csr_pad, 0);
        k_spmm_p<<<spmm_grid, 256, 0, stream>>>(slot[3], slot[2], slot[4],
                                                cnt, csr_pad, 0);
        k_spmm_p<<<spmm_grid, 256, 0, stream>>>(slot[4], slot[3], slot[5],
                                                cnt, csr_pad, 0);
        k_gemm_mfma<<<gemm_grid, 256, 0, stream>>>(xh, wfr, out);
    } else if (ws_size >= 6 * bufH + wfB + csrB) {
        // ---- R11-verified fallback: packed CSR, 10 graph nodes ----
        ushort* xh  = (ushort*)ws;
        ushort* wfr = (ushort*)(ws + 6 * bufH);
        int*    rowptr = (int*)(ws + 6 * bufH + wfB);
        int*    fill   = rowptr + (Mn + 4);              // doubles as wcur
        int2*   csr    = (int2*)(fill + Mn);
        int*    bsum   = (int*)csr;                      // scan scratch in csr buf
        ushort* slot[6];
        for (int l = 0; l < 6; ++l) slot[l] = xh + (size_t)l * Mn * Cn;

        hipMemsetAsync(fill, 0, Mn * sizeof(int), stream);
        k_hist<<<HGRID, 256, 0, stream>>>(edge_rows, fill);
        k_scan_part<<<NB, 256, 0, stream>>>(fill, rowptr, bsum);
        k_scan_add2<<<NB, 256, 0, stream>>>(rowptr, bsum, fill);
        k_fused_aux<<<SCGRID + WFGRID + TGRID, 256, 0, stream>>>(
            edge_rows, edge_cols, edge_vals, fill, csr, W, wfr, x, slot[0]);
        k_spmm_h<<<spmm_grid, 256, 0, stream>>>(slot[0], slot[0], slot[1],
                                                rowptr, csr, 1);
        k_spmm_h<<<spmm_grid, 256, 0, stream>>>(slot[1], slot[0], slot[2],
                                                rowptr, csr, 0);
        k_spmm_h<<<spmm_grid, 256, 0, stream>>>(slot[2], slot[1], slot[3],
                                                rowptr, csr, 0);
        k_spmm_h<<<spmm_grid, 256, 0, stream>>>(slot[3], slot[2], slot[4],
                                                rowptr, csr, 0);
        k_spmm_h<<<spmm_grid, 256, 0, stream>>>(slot[4], slot[3], slot[5],
                                                rowptr, csr, 0);
        k_gemm_mfma<<<gemm_grid, 256, 0, stream>>>(xh, wfr, out);
    } else {
        // fp32 fallback: 3 rotating fp32 buffers + fp32 vector GEMM
        float* buf0 = (float*)(ws);
        float* buf1 = (float*)(ws + bufB);
        float* buf2 = (float*)(ws + 2 * bufB);
        int*   rowptr = (int*)(ws + 3 * bufB);
        int*   fill   = rowptr + (Mn + 4);
        int2*  csr    = (int2*)(fill + Mn);
        int*   bsum   = (int*)csr;
        hipMemsetAsync(fill, 0, Mn * sizeof(int), stream);
        k_hist<<<HGRID, 256, 0, stream>>>(edge_rows, fill);
        k_scan_part<<<NB, 256, 0, stream>>>(fill, rowptr, bsum);
        k_scan_add2<<<NB, 256, 0, stream>>>(rowptr, bsum, fill);
        k_scatter<<<SCGRID, 256, 0, stream>>>(edge_rows, edge_cols,
                                              edge_vals, fill, csr);
        k_transpose_f<<<Mn, 512, 0, stream>>>(x, buf0);
        k_spmm_f32<<<Mn / 4, 256, 0, stream>>>((const float4*)buf0, (const float4*)buf0,
                                               (float4*)buf1, rowptr, csr, 1);
        k_gemm2<<<Mn / 4, 256, 0, stream>>>(buf0, buf1, W, out, 0, 1, 0);
        k_spmm_f32<<<Mn / 4, 256, 0, stream>>>((const float4*)buf1, (const float4*)buf0,
                                               (float4*)buf2, rowptr, csr, 0);
        k_spmm_f32<<<Mn / 4, 256, 0, stream>>>((const float4*)buf2, (const float4*)buf1,
                                               (float4*)buf0, rowptr, csr, 0);
        k_gemm2<<<Mn / 4, 256, 0, stream>>>(buf2, buf0, W, out, 2, 3, 1);
        k_spmm_f32<<<Mn / 4, 256, 0, stream>>>((const float4*)buf0, (const float4*)buf2,
                                               (float4*)buf1, rowptr, csr, 0);
        k_spmm_f32<<<Mn / 4, 256, 0, stream>>>((const float4*)buf1, (const float4*)buf0,
                                               (float4*)buf2, rowptr, csr, 0);
        k_gemm2<<<Mn / 4, 256, 0, stream>>>(buf1, buf2, W, out, 4, 5, 1);
    }
}